// Round 1
// baseline (621.264 us; speedup 1.0000x reference)
//
#include <hip/hip_runtime.h>

typedef unsigned short u16;
typedef unsigned int u32;
typedef __attribute__((ext_vector_type(8))) short s16x8;
typedef __attribute__((ext_vector_type(4))) float f32x4;

#define GAS __attribute__((address_space(1)))
#define LAS __attribute__((address_space(3)))

// ---- constants ----
#define BB 4
#define LL 8192
#define DD 1024
#define NH 16
#define HD 64
#define MROWS (BB * LL)          // 32768
#define NCOLS (3 * DD)           // 3072

__device__ __forceinline__ u16 f2bf(float f) {
  u32 u = __builtin_bit_cast(u32, f);
  u32 r = (u + 0x7FFFu + ((u >> 16) & 1u)) >> 16;
  return (u16)r;
}
__device__ __forceinline__ float bf2f(u32 lo) {
  return __builtin_bit_cast(float, lo << 16);
}

__device__ __forceinline__ void async16(const void* g, void* l) {
  __builtin_amdgcn_global_load_lds((const GAS u32*)g, (LAS u32*)l, 16, 0, 0);
}

// mask encoding modes: 0 = int32, 1 = float32, 2 = uint8
__device__ __forceinline__ bool get_mask(const void* mp, int row, int mode) {
  if (mode == 2) return ((const unsigned char*)mp)[row] != 0;
  if (mode == 1) return ((const float*)mp)[row] != 0.f;
  return ((const int*)mp)[row] != 0;
}

// Classify mask dtype by inspecting first 8192 32-bit words (32 KB — safe
// to read under any of the three candidate layouts).
__global__ void detect_mask(const u32* __restrict__ m, int* __restrict__ flag) {
  int i = blockIdx.x * 256 + threadIdx.x;  // 8192 threads
  u32 v = m[i];
  int f = 0;
  if (v == 0x3F800000u) f = 1;       // looks like float 1.0
  else if (v > 1u) f = 2;            // packed bytes -> uint8
  if (f) atomicMax(flag, f);
}

// query fp32 -> bf16
__global__ void cvt_q(const float* __restrict__ q, u16* __restrict__ qb, int n4) {
  int i = blockIdx.x * 256 + threadIdx.x;
  if (i >= n4) return;
  float4 v = ((const float4*)q)[i];
  u16 o0 = f2bf(v.x), o1 = f2bf(v.y), o2 = f2bf(v.z), o3 = f2bf(v.w);
  u32 lo = (u32)o0 | ((u32)o1 << 16);
  u32 hi = (u32)o2 | ((u32)o3 << 16);
  ((u32*)qb)[2 * i] = lo;
  ((u32*)qb)[2 * i + 1] = hi;
}

// Build WbT[n][k] = W{q,k,v}[k][n mod 1024] as bf16 (transposed, 32x32 LDS tiles)
__global__ void build_wbt(const float* __restrict__ Wq, const float* __restrict__ Wk,
                          const float* __restrict__ Wv, u16* __restrict__ WbT) {
  __shared__ float t[32][33];
  const int n0 = blockIdx.x * 32;  // 0..3071
  const int k0 = blockIdx.y * 32;  // 0..1023
  const int sec = n0 >> 10;
  const float* W = sec == 0 ? Wq : (sec == 1 ? Wk : Wv);
  const int nloc = n0 & 1023;
  const int tx = threadIdx.x, ty = threadIdx.y;  // 32 x 8
#pragma unroll
  for (int j = 0; j < 32; j += 8)
    t[ty + j][tx] = W[(size_t)(k0 + ty + j) * DD + nloc + tx];
  __syncthreads();
#pragma unroll
  for (int j = 0; j < 32; j += 8)
    WbT[(size_t)(n0 + ty + j) * DD + k0 + tx] = f2bf(t[tx][ty + j]);
}

__global__ void build_bcat(const float* __restrict__ bq, const float* __restrict__ bk,
                           const float* __restrict__ bv, float* __restrict__ bcat) {
  int i = blockIdx.x * 256 + threadIdx.x;
  if (i < 1024) bcat[i] = bq[i];
  else if (i < 2048) bcat[i] = bk[i - 1024];
  else if (i < 3072) bcat[i] = bv[i - 2048];
}

// Fused QKV GEMM: C[m][n] = sum_k qb[m][k] * WbT[n][k]; epilogue computes
// phiQ / phiK (bf16) and the per-(row,head) V row-sum sV (fp32).
__global__ __launch_bounds__(256) void gemm_qkv(
    const u16* __restrict__ qb, const u16* __restrict__ WbT,
    const float* __restrict__ bcat, const void* __restrict__ maskp,
    const int* __restrict__ mmode,
    u16* __restrict__ phiQ, u16* __restrict__ phiK, float* __restrict__ sV) {
  __shared__ u16 ldsA[128 * 64];
  __shared__ u16 ldsB[128 * 64];
  const int tid = threadIdx.x;
  const int lane = tid & 63;
  const int w = tid >> 6;
  const int wm = w & 1, wn = w >> 1;
  const int row0 = blockIdx.x * 128;
  const int col0 = blockIdx.y * 128;

  f32x4 acc[4][4] = {};

  const int r_l = tid >> 3;            // 0..31: row within 32-row stripe
  const int kcol = (tid & 7) << 3;     // 0,8,..,56
  const u16* gA = qb + (size_t)(row0 + r_l) * DD + kcol;
  const u16* gB = WbT + (size_t)(col0 + r_l) * DD + kcol;

  for (int k0 = 0; k0 < DD; k0 += 64) {
    __syncthreads();
#pragma unroll
    for (int i = 0; i < 4; ++i) {
      async16(gA + (size_t)i * 32 * DD + k0, ldsA + (i * 256 + tid) * 8);
      async16(gB + (size_t)i * 32 * DD + k0, ldsB + (i * 256 + tid) * 8);
    }
    __syncthreads();
#pragma unroll
    for (int kk = 0; kk < 2; ++kk) {
      s16x8 af[4], bfr[4];
      const int ko = kk * 32 + (lane >> 4) * 8;
#pragma unroll
      for (int mi = 0; mi < 4; ++mi)
        af[mi] = *(const s16x8*)(ldsA + (wm * 64 + mi * 16 + (lane & 15)) * 64 + ko);
#pragma unroll
      for (int ni = 0; ni < 4; ++ni)
        bfr[ni] = *(const s16x8*)(ldsB + (wn * 64 + ni * 16 + (lane & 15)) * 64 + ko);
#pragma unroll
      for (int mi = 0; mi < 4; ++mi)
#pragma unroll
        for (int ni = 0; ni < 4; ++ni)
          acc[mi][ni] = __builtin_amdgcn_mfma_f32_16x16x32_bf16(af[mi], bfr[ni], acc[mi][ni], 0, 0, 0);
    }
  }

  const int mode = *mmode;
  const int lanec = lane & 15, laneq = lane >> 4;
  const int sect = col0 >> 10;            // 0=q, 1=k, 2=v (128-col block never crosses)
  const int wcol0 = col0 + wn * 64;       // wave covers exactly one 64-col head span
  if (sect < 2) {
    u16* dst = sect == 0 ? phiQ : phiK;
#pragma unroll
    for (int mi = 0; mi < 4; ++mi) {
#pragma unroll
      for (int r = 0; r < 4; ++r) {
        const int row = row0 + wm * 64 + mi * 16 + laneq * 4 + r;
        const bool msk = (sect == 1) && get_mask(maskp, row, mode);
#pragma unroll
        for (int ni = 0; ni < 4; ++ni) {
          const int col = wcol0 + ni * 16 + lanec;
          float v = acc[mi][ni][r] + bcat[col];
          float phi = v > 0.f ? v + 1.f : __expf(v);
          if (msk) phi = 0.f;
          dst[(size_t)row * DD + (col & 1023)] = f2bf(phi);
        }
      }
    }
  } else {
    const int head = (wcol0 - 2048) >> 6;
#pragma unroll
    for (int mi = 0; mi < 4; ++mi) {
#pragma unroll
      for (int r = 0; r < 4; ++r) {
        const int row = row0 + wm * 64 + mi * 16 + laneq * 4 + r;
        const bool msk = get_mask(maskp, row, mode);
        float s = 0.f;
#pragma unroll
        for (int ni = 0; ni < 4; ++ni) {
          const int col = wcol0 + ni * 16 + lanec;
          s += acc[mi][ni][r] + bcat[col];
        }
        if (msk) s = 0.f;
        s += __shfl_xor(s, 1);
        s += __shfl_xor(s, 2);
        s += __shfl_xor(s, 4);
        s += __shfl_xor(s, 8);
        if (lanec == 0) sV[(size_t)row * NH + head] = s;
      }
    }
  }
}

// kv_sum[b,n,hd] = sum_l phiK[b,l,n,hd] * sV[b,l,n]
__global__ void kv_reduce(const u16* __restrict__ phiK, const float* __restrict__ sV,
                          float* __restrict__ kv_sum) {
  const int bh = blockIdx.x;  // b*16 + n
  const int b = bh >> 4, n = bh & 15;
  const int l0 = blockIdx.y * 512;
  const int tid = threadIdx.x;
  const int h2 = tid & 31;    // bf16 pair within head-dim
  const int rg = tid >> 5;    // 0..7
  float ax = 0.f, ay = 0.f;
  const size_t base_row = (size_t)b * LL + l0;
  for (int i = 0; i < 64; ++i) {
    const size_t row = base_row + rg + 8 * i;
    u32 u = *(const u32*)(phiK + row * DD + n * HD + h2 * 2);
    float s = sV[row * NH + n];
    ax += bf2f(u & 0xffffu) * s;
    ay += bf2f(u >> 16) * s;
  }
  __shared__ float red[8][64];
  red[rg][h2 * 2] = ax;
  red[rg][h2 * 2 + 1] = ay;
  __syncthreads();
  if (tid < 64) {
    float s = 0.f;
#pragma unroll
    for (int r = 0; r < 8; ++r) s += red[r][tid];
    atomicAdd(&kv_sum[b * DD + n * HD + tid], s);
  }
}

// out[b,l,d] = phiQ[b,l,d] * kv_sum[b,d]
__global__ void finalize(const u16* __restrict__ phiQ, const float* __restrict__ kv_sum,
                         float* __restrict__ out) {
  const size_t i = (size_t)(blockIdx.x * 256 + threadIdx.x) * 4;
  const size_t b = i >> 23;  // / (8192*1024)
  const int d = (int)(i & 1023);
  u32 p0 = *(const u32*)(phiQ + i);
  u32 p1 = *(const u32*)(phiQ + i + 2);
  float4 kv = *(const float4*)(kv_sum + b * DD + d);
  float4 o;
  o.x = bf2f(p0 & 0xffffu) * kv.x;
  o.y = bf2f(p0 >> 16) * kv.y;
  o.z = bf2f(p1 & 0xffffu) * kv.z;
  o.w = bf2f(p1 >> 16) * kv.w;
  *(float4*)(out + i) = o;
}

extern "C" void kernel_launch(void* const* d_in, const int* in_sizes, int n_in,
                              void* d_out, int out_size, void* d_ws, size_t ws_size,
                              hipStream_t stream) {
  const float* query = (const float*)d_in[0];
  const void* maskp = d_in[1];
  const float* Wq = (const float*)d_in[2];
  const float* bq = (const float*)d_in[3];
  const float* Wk = (const float*)d_in[4];
  const float* bk = (const float*)d_in[5];
  const float* Wv = (const float*)d_in[6];
  const float* bv = (const float*)d_in[7];
  float* out = (float*)d_out;

  char* ws = (char*)d_ws;
  u16* qb = (u16*)ws;            ws += (size_t)MROWS * DD * 2;      // 64 MB
  u16* WbT = (u16*)ws;           ws += (size_t)NCOLS * DD * 2;      // 6 MB
  u16* phiQ = (u16*)ws;          ws += (size_t)MROWS * DD * 2;      // 64 MB
  u16* phiK = (u16*)ws;          ws += (size_t)MROWS * DD * 2;      // 64 MB
  float* sV = (float*)ws;        ws += (size_t)MROWS * NH * 4;      // 2 MB
  float* bcat = (float*)ws;      ws += (size_t)NCOLS * 4;
  float* kv = (float*)ws;        ws += (size_t)BB * DD * 4;         // 16 KB
  int* mflag = (int*)ws;         ws += 256;

  // zero kv_sum + mask-mode flag (ws is poisoned 0xAA before every launch)
  hipMemsetAsync(kv, 0, (size_t)BB * DD * 4 + 256, stream);

  detect_mask<<<32, 256, 0, stream>>>((const u32*)maskp, mflag);
  cvt_q<<<(MROWS * (DD / 4) + 255) / 256, 256, 0, stream>>>(query, qb, MROWS * (DD / 4));
  build_wbt<<<dim3(NCOLS / 32, DD / 32), dim3(32, 8), 0, stream>>>(Wq, Wk, Wv, WbT);
  build_bcat<<<(NCOLS + 255) / 256, 256, 0, stream>>>(bq, bk, bv, bcat);
  gemm_qkv<<<dim3(MROWS / 128, NCOLS / 128), 256, 0, stream>>>(
      qb, WbT, bcat, maskp, mflag, phiQ, phiK, sV);
  kv_reduce<<<dim3(BB * NH, LL / 512), 256, 0, stream>>>(phiK, sV, kv);
  finalize<<<(MROWS * DD / 4) / 256, 256, 0, stream>>>(phiQ, kv, out);
}

// Round 2
// 544.593 us; speedup vs baseline: 1.1408x; 1.1408x over previous
//
#include <hip/hip_runtime.h>

typedef unsigned short u16;
typedef unsigned int u32;
typedef __attribute__((ext_vector_type(8))) short s16x8;
typedef __attribute__((ext_vector_type(4))) float f32x4;

#define GAS __attribute__((address_space(1)))
#define LAS __attribute__((address_space(3)))

// ---- constants ----
#define BB 4
#define LL 8192
#define DD 1024
#define NH 16
#define HD 64
#define MROWS (BB * LL)          // 32768
#define NCOLS (3 * DD)           // 3072

__device__ __forceinline__ u16 f2bf(float f) {
  u32 u = __builtin_bit_cast(u32, f);
  u32 r = (u + 0x7FFFu + ((u >> 16) & 1u)) >> 16;
  return (u16)r;
}
__device__ __forceinline__ float bf2f(u32 lo) {
  return __builtin_bit_cast(float, lo << 16);
}

__device__ __forceinline__ void async16(const void* g, void* l) {
  __builtin_amdgcn_global_load_lds((const GAS u32*)g, (LAS u32*)l, 16, 0, 0);
}

// mask encoding modes: 0 = int32, 1 = float32, 2 = uint8
__device__ __forceinline__ bool get_mask(const void* mp, int row, int mode) {
  if (mode == 2) return ((const unsigned char*)mp)[row] != 0;
  if (mode == 1) return ((const float*)mp)[row] != 0.f;
  return ((const int*)mp)[row] != 0;
}

// Classify mask dtype by inspecting first 8192 32-bit words (32 KB — safe
// to read under any of the three candidate layouts).
__global__ void detect_mask(const u32* __restrict__ m, int* __restrict__ flag) {
  int i = blockIdx.x * 256 + threadIdx.x;  // 8192 threads
  u32 v = m[i];
  int f = 0;
  if (v == 0x3F800000u) f = 1;       // looks like float 1.0
  else if (v > 1u) f = 2;            // packed bytes -> uint8
  if (f) atomicMax(flag, f);
}

// query fp32 -> bf16
__global__ void cvt_q(const float* __restrict__ q, u16* __restrict__ qb, int n4) {
  int i = blockIdx.x * 256 + threadIdx.x;
  if (i >= n4) return;
  float4 v = ((const float4*)q)[i];
  u16 o0 = f2bf(v.x), o1 = f2bf(v.y), o2 = f2bf(v.z), o3 = f2bf(v.w);
  u32 lo = (u32)o0 | ((u32)o1 << 16);
  u32 hi = (u32)o2 | ((u32)o3 << 16);
  ((u32*)qb)[2 * i] = lo;
  ((u32*)qb)[2 * i + 1] = hi;
}

// Build WbT[n][k] = W{q,k,v}[k][n mod 1024] as bf16 (transposed, 32x32 LDS tiles)
__global__ void build_wbt(const float* __restrict__ Wq, const float* __restrict__ Wk,
                          const float* __restrict__ Wv, u16* __restrict__ WbT) {
  __shared__ float t[32][33];
  const int n0 = blockIdx.x * 32;  // 0..3071
  const int k0 = blockIdx.y * 32;  // 0..1023
  const int sec = n0 >> 10;
  const float* W = sec == 0 ? Wq : (sec == 1 ? Wk : Wv);
  const int nloc = n0 & 1023;
  const int tx = threadIdx.x, ty = threadIdx.y;  // 32 x 8
#pragma unroll
  for (int j = 0; j < 32; j += 8)
    t[ty + j][tx] = W[(size_t)(k0 + ty + j) * DD + nloc + tx];
  __syncthreads();
#pragma unroll
  for (int j = 0; j < 32; j += 8)
    WbT[(size_t)(n0 + ty + j) * DD + k0 + tx] = f2bf(t[tx][ty + j]);
}

__global__ void build_bcat(const float* __restrict__ bq, const float* __restrict__ bk,
                           const float* __restrict__ bv, float* __restrict__ bcat) {
  int i = blockIdx.x * 256 + threadIdx.x;
  if (i < 1024) bcat[i] = bq[i];
  else if (i < 2048) bcat[i] = bk[i - 1024];
  else if (i < 3072) bcat[i] = bv[i - 2048];
}

// Fused QKV GEMM: C[m][n] = sum_k qb[m][k] * WbT[n][k]; epilogue computes
// phiQ / phiK (bf16) and the per-(row,head) V row-sum sV (fp32).
//
// LDS layout is XOR-swizzled: within each 128-row x 64-col tile, row `r`'s
// 8-element k-segment `seg` lives at slot `seg ^ (r & 7)`. The stager keeps
// its LDS destination contiguous in tid (required by global_load_lds) and
// instead picks WHICH global segment each lane fetches; fragment ds_read_b128
// then spreads 16 lanes over 8 distinct 16B slots -> 2-way (free) instead of
// 16-way bank conflicts.
__global__ __launch_bounds__(256) void gemm_qkv(
    const u16* __restrict__ qb, const u16* __restrict__ WbT,
    const float* __restrict__ bcat, const void* __restrict__ maskp,
    const int* __restrict__ mmode,
    u16* __restrict__ phiQ, u16* __restrict__ phiK, float* __restrict__ sV) {
  __shared__ u16 ldsA[128 * 64];
  __shared__ u16 ldsB[128 * 64];
  const int tid = threadIdx.x;
  const int lane = tid & 63;
  const int w = tid >> 6;
  const int wm = w & 1, wn = w >> 1;
  const int row0 = blockIdx.x * 128;
  const int col0 = blockIdx.y * 128;

  f32x4 acc[4][4] = {};

  const int r_l = tid >> 3;            // 0..31: row within 32-row stripe
  const int slot = tid & 7;            // LDS slot this lane fills
  const int seg = slot ^ (r_l & 7);    // global k-segment it fetches (swizzle)
  const u16* gA = qb + (size_t)(row0 + r_l) * DD + seg * 8;
  const u16* gB = WbT + (size_t)(col0 + r_l) * DD + seg * 8;

  for (int k0 = 0; k0 < DD; k0 += 64) {
    __syncthreads();
#pragma unroll
    for (int i = 0; i < 4; ++i) {
      async16(gA + (size_t)i * 32 * DD + k0, ldsA + (i * 256 + tid) * 8);
      async16(gB + (size_t)i * 32 * DD + k0, ldsB + (i * 256 + tid) * 8);
    }
    __syncthreads();
#pragma unroll
    for (int kk = 0; kk < 2; ++kk) {
      s16x8 af[4], bfr[4];
      const int segk = kk * 4 + (lane >> 4);  // k-segment index within stage
#pragma unroll
      for (int mi = 0; mi < 4; ++mi) {
        const int r = wm * 64 + mi * 16 + (lane & 15);
        af[mi] = *(const s16x8*)(ldsA + r * 64 + (segk ^ (r & 7)) * 8);
      }
#pragma unroll
      for (int ni = 0; ni < 4; ++ni) {
        const int r = wn * 64 + ni * 16 + (lane & 15);
        bfr[ni] = *(const s16x8*)(ldsB + r * 64 + (segk ^ (r & 7)) * 8);
      }
#pragma unroll
      for (int mi = 0; mi < 4; ++mi)
#pragma unroll
        for (int ni = 0; ni < 4; ++ni)
          acc[mi][ni] = __builtin_amdgcn_mfma_f32_16x16x32_bf16(af[mi], bfr[ni], acc[mi][ni], 0, 0, 0);
    }
  }

  const int mode = *mmode;
  const int lanec = lane & 15, laneq = lane >> 4;
  const int sect = col0 >> 10;            // 0=q, 1=k, 2=v (128-col block never crosses)
  const int wcol0 = col0 + wn * 64;       // wave covers exactly one 64-col head span
  if (sect < 2) {
    u16* dst = sect == 0 ? phiQ : phiK;
#pragma unroll
    for (int mi = 0; mi < 4; ++mi) {
#pragma unroll
      for (int r = 0; r < 4; ++r) {
        const int row = row0 + wm * 64 + mi * 16 + laneq * 4 + r;
        const bool msk = (sect == 1) && get_mask(maskp, row, mode);
#pragma unroll
        for (int ni = 0; ni < 4; ++ni) {
          const int col = wcol0 + ni * 16 + lanec;
          float v = acc[mi][ni][r] + bcat[col];
          float phi = v > 0.f ? v + 1.f : __expf(v);
          if (msk) phi = 0.f;
          dst[(size_t)row * DD + (col & 1023)] = f2bf(phi);
        }
      }
    }
  } else {
    const int head = (wcol0 - 2048) >> 6;
#pragma unroll
    for (int mi = 0; mi < 4; ++mi) {
#pragma unroll
      for (int r = 0; r < 4; ++r) {
        const int row = row0 + wm * 64 + mi * 16 + laneq * 4 + r;
        const bool msk = get_mask(maskp, row, mode);
        float s = 0.f;
#pragma unroll
        for (int ni = 0; ni < 4; ++ni) {
          const int col = wcol0 + ni * 16 + lanec;
          s += acc[mi][ni][r] + bcat[col];
        }
        if (msk) s = 0.f;
        s += __shfl_xor(s, 1);
        s += __shfl_xor(s, 2);
        s += __shfl_xor(s, 4);
        s += __shfl_xor(s, 8);
        if (lanec == 0) sV[(size_t)row * NH + head] = s;
      }
    }
  }
}

// kv_sum[b,n,hd] = sum_l phiK[b,l,n,hd] * sV[b,l,n]
__global__ void kv_reduce(const u16* __restrict__ phiK, const float* __restrict__ sV,
                          float* __restrict__ kv_sum) {
  const int bh = blockIdx.x;  // b*16 + n
  const int b = bh >> 4, n = bh & 15;
  const int l0 = blockIdx.y * 512;
  const int tid = threadIdx.x;
  const int h2 = tid & 31;    // bf16 pair within head-dim
  const int rg = tid >> 5;    // 0..7
  float ax = 0.f, ay = 0.f;
  const size_t base_row = (size_t)b * LL + l0;
  for (int i = 0; i < 64; ++i) {
    const size_t row = base_row + rg + 8 * i;
    u32 u = *(const u32*)(phiK + row * DD + n * HD + h2 * 2);
    float s = sV[row * NH + n];
    ax += bf2f(u & 0xffffu) * s;
    ay += bf2f(u >> 16) * s;
  }
  __shared__ float red[8][64];
  red[rg][h2 * 2] = ax;
  red[rg][h2 * 2 + 1] = ay;
  __syncthreads();
  if (tid < 64) {
    float s = 0.f;
#pragma unroll
    for (int r = 0; r < 8; ++r) s += red[r][tid];
    atomicAdd(&kv_sum[b * DD + n * HD + tid], s);
  }
}

// out[b,l,d] = phiQ[b,l,d] * kv_sum[b,d]
__global__ void finalize(const u16* __restrict__ phiQ, const float* __restrict__ kv_sum,
                         float* __restrict__ out) {
  const size_t i = (size_t)(blockIdx.x * 256 + threadIdx.x) * 4;
  const size_t b = i >> 23;  // / (8192*1024)
  const int d = (int)(i & 1023);
  u32 p0 = *(const u32*)(phiQ + i);
  u32 p1 = *(const u32*)(phiQ + i + 2);
  float4 kv = *(const float4*)(kv_sum + b * DD + d);
  float4 o;
  o.x = bf2f(p0 & 0xffffu) * kv.x;
  o.y = bf2f(p0 >> 16) * kv.y;
  o.z = bf2f(p1 & 0xffffu) * kv.z;
  o.w = bf2f(p1 >> 16) * kv.w;
  *(float4*)(out + i) = o;
}

extern "C" void kernel_launch(void* const* d_in, const int* in_sizes, int n_in,
                              void* d_out, int out_size, void* d_ws, size_t ws_size,
                              hipStream_t stream) {
  const float* query = (const float*)d_in[0];
  const void* maskp = d_in[1];
  const float* Wq = (const float*)d_in[2];
  const float* bq = (const float*)d_in[3];
  const float* Wk = (const float*)d_in[4];
  const float* bk = (const float*)d_in[5];
  const float* Wv = (const float*)d_in[6];
  const float* bv = (const float*)d_in[7];
  float* out = (float*)d_out;

  char* ws = (char*)d_ws;
  u16* qb = (u16*)ws;            ws += (size_t)MROWS * DD * 2;      // 64 MB
  u16* WbT = (u16*)ws;           ws += (size_t)NCOLS * DD * 2;      // 6 MB
  u16* phiQ = (u16*)ws;          ws += (size_t)MROWS * DD * 2;      // 64 MB
  u16* phiK = (u16*)ws;          ws += (size_t)MROWS * DD * 2;      // 64 MB
  float* sV = (float*)ws;        ws += (size_t)MROWS * NH * 4;      // 2 MB
  float* bcat = (float*)ws;      ws += (size_t)NCOLS * 4;
  float* kv = (float*)ws;        ws += (size_t)BB * DD * 4;         // 16 KB
  int* mflag = (int*)ws;         ws += 256;

  // zero kv_sum + mask-mode flag (ws is poisoned 0xAA before every launch)
  hipMemsetAsync(kv, 0, (size_t)BB * DD * 4 + 256, stream);

  detect_mask<<<32, 256, 0, stream>>>((const u32*)maskp, mflag);
  cvt_q<<<(MROWS * (DD / 4) + 255) / 256, 256, 0, stream>>>(query, qb, MROWS * (DD / 4));
  build_wbt<<<dim3(NCOLS / 32, DD / 32), dim3(32, 8), 0, stream>>>(Wq, Wk, Wv, WbT);
  build_bcat<<<(NCOLS + 255) / 256, 256, 0, stream>>>(bq, bk, bv, bcat);
  gemm_qkv<<<dim3(MROWS / 128, NCOLS / 128), 256, 0, stream>>>(
      qb, WbT, bcat, maskp, mflag, phiQ, phiK, sV);
  kv_reduce<<<dim3(BB * NH, LL / 512), 256, 0, stream>>>(phiK, sV, kv);
  finalize<<<(MROWS * DD / 4) / 256, 256, 0, stream>>>(phiQ, kv, out);
}

// Round 3
// 483.052 us; speedup vs baseline: 1.2861x; 1.1274x over previous
//
#include <hip/hip_runtime.h>

typedef unsigned short u16;
typedef unsigned int u32;
typedef __attribute__((ext_vector_type(8))) short s16x8;
typedef __attribute__((ext_vector_type(4))) float f32x4;

#define GAS __attribute__((address_space(1)))
#define LAS __attribute__((address_space(3)))

// ---- constants ----
#define BB 4
#define LL 8192
#define DD 1024
#define NH 16
#define HD 64
#define MROWS (BB * LL)          // 32768
#define NWBT 2176                // 1024 Q + 1024 K + 16 WvS + 112 zero-pad

__device__ __forceinline__ u16 f2bf(float f) {
  u32 u = __builtin_bit_cast(u32, f);
  u32 r = (u + 0x7FFFu + ((u >> 16) & 1u)) >> 16;
  return (u16)r;
}
__device__ __forceinline__ float bf2f(u32 lo) {
  return __builtin_bit_cast(float, lo << 16);
}

__device__ __forceinline__ void async16(const void* g, void* l) {
  __builtin_amdgcn_global_load_lds((const GAS u32*)g, (LAS u32*)l, 16, 0, 0);
}

// mask encoding modes: 0 = int32, 1 = float32, 2 = uint8
__device__ __forceinline__ bool get_mask(const void* mp, int row, int mode) {
  if (mode == 2) return ((const unsigned char*)mp)[row] != 0;
  if (mode == 1) return ((const float*)mp)[row] != 0.f;
  return ((const int*)mp)[row] != 0;
}

// Classify mask dtype by inspecting first 8192 32-bit words.
__global__ void detect_mask(const u32* __restrict__ m, int* __restrict__ flag) {
  int i = blockIdx.x * 256 + threadIdx.x;  // 8192 threads
  u32 v = m[i];
  int f = 0;
  if (v == 0x3F800000u) f = 1;       // looks like float 1.0
  else if (v > 1u) f = 2;            // packed bytes -> uint8
  if (f) atomicMax(flag, f);
}

// query fp32 -> bf16
__global__ void cvt_q(const float* __restrict__ q, u16* __restrict__ qb, int n4) {
  int i = blockIdx.x * 256 + threadIdx.x;
  if (i >= n4) return;
  float4 v = ((const float4*)q)[i];
  u16 o0 = f2bf(v.x), o1 = f2bf(v.y), o2 = f2bf(v.z), o3 = f2bf(v.w);
  ((u32*)qb)[2 * i] = (u32)o0 | ((u32)o1 << 16);
  ((u32*)qb)[2 * i + 1] = (u32)o2 | ((u32)o3 << 16);
}

// Build WbT[n][k] = W{q,k}[k][n mod 1024] as bf16 (transposed, 32x32 LDS tiles)
__global__ void build_wbt(const float* __restrict__ Wq, const float* __restrict__ Wk,
                          u16* __restrict__ WbT) {
  __shared__ float t[32][33];
  const int n0 = blockIdx.x * 32;  // 0..2047
  const int k0 = blockIdx.y * 32;  // 0..1023
  const float* W = (n0 >> 10) == 0 ? Wq : Wk;
  const int nloc = n0 & 1023;
  const int tx = threadIdx.x, ty = threadIdx.y;  // 32 x 8
#pragma unroll
  for (int j = 0; j < 32; j += 8)
    t[ty + j][tx] = W[(size_t)(k0 + ty + j) * DD + nloc + tx];
  __syncthreads();
#pragma unroll
  for (int j = 0; j < 32; j += 8)
    WbT[(size_t)(n0 + ty + j) * DD + k0 + tx] = f2bf(t[tx][ty + j]);
}

// WbT rows 2048..2063: WvS[h][k] = sum_{j<64} Wv[k][h*64+j]  (bf16)
__global__ void build_wvs(const float* __restrict__ Wv, u16* __restrict__ WbT) {
  int i = blockIdx.x * 256 + threadIdx.x;  // 16384: k = i>>4, h = i&15
  int k = i >> 4, h = i & 15;
  float s = 0.f;
  const float* p = Wv + (size_t)k * DD + h * HD;
#pragma unroll 8
  for (int j = 0; j < 64; ++j) s += p[j];
  WbT[(size_t)(2048 + h) * DD + k] = f2bf(s);
}

// bcat[0..1023]=bq, [1024..2047]=bk, [2048+h]=sum_{j<64} bv[h*64+j], rest 0
__global__ void build_bcat(const float* __restrict__ bq, const float* __restrict__ bk,
                           const float* __restrict__ bv, float* __restrict__ bcat) {
  int i = blockIdx.x * 256 + threadIdx.x;
  if (i < 1024) bcat[i] = bq[i];
  else if (i < 2048) bcat[i] = bk[i - 1024];
  else if (i < 2064) {
    float s = 0.f;
    const float* p = bv + (i - 2048) * HD;
#pragma unroll 8
    for (int j = 0; j < 64; ++j) s += p[j];
    bcat[i] = s;
  } else if (i < NWBT) bcat[i] = 0.f;
}

// Fused projection GEMM: C[m][n] = sum_k qb[m][k] * WbT[n][k].
// phase 0 (grid.y = 9): Q col-tiles (0..7) -> phiQ (bf16); WvS tile (y==8,
//   col0=2048) -> sV[row][head] fp32 (masked rows -> 0).
// phase 1 (grid.y = 8): K col-tiles (col0 = 1024 + y*128) -> phiK computed in
//   registers, multiplied by sV and row-reduced; partial kv_sum atomicAdd'ed.
//   phiK never touches memory.
// LDS XOR-swizzle: row r's k-segment `seg` lives at slot seg^(r&7) -> the
// 16-lane fragment ds_read_b128 spreads over 8 slots (2-way = free).
__global__ __launch_bounds__(256) void gemm_qkv(
    const u16* __restrict__ qb, const u16* __restrict__ WbT,
    const float* __restrict__ bcat, const void* __restrict__ maskp,
    const int* __restrict__ mmode,
    u16* __restrict__ phiQ, float* __restrict__ sV, float* __restrict__ kv,
    int phase) {
  __shared__ u16 ldsA[128 * 64];
  __shared__ u16 ldsB[128 * 64];
  const int tid = threadIdx.x;
  const int lane = tid & 63;
  const int w = tid >> 6;
  const int wm = w & 1, wn = w >> 1;
  const int row0 = blockIdx.x * 128;
  const int cy = blockIdx.y;
  const int col0 = phase == 0 ? (cy == 8 ? 2048 : cy * 128) : 1024 + cy * 128;

  f32x4 acc[4][4] = {};

  const int r_l = tid >> 3;            // 0..31: row within 32-row stripe
  const int slot = tid & 7;            // LDS slot this lane fills
  const int seg = slot ^ (r_l & 7);    // global k-segment it fetches (swizzle)
  const u16* gA = qb + (size_t)(row0 + r_l) * DD + seg * 8;
  const u16* gB = WbT + (size_t)(col0 + r_l) * DD + seg * 8;

  for (int k0 = 0; k0 < DD; k0 += 64) {
    __syncthreads();
#pragma unroll
    for (int i = 0; i < 4; ++i) {
      async16(gA + (size_t)i * 32 * DD + k0, ldsA + (i * 256 + tid) * 8);
      async16(gB + (size_t)i * 32 * DD + k0, ldsB + (i * 256 + tid) * 8);
    }
    __syncthreads();
#pragma unroll
    for (int kk = 0; kk < 2; ++kk) {
      s16x8 af[4], bfr[4];
      const int segk = kk * 4 + (lane >> 4);  // k-segment index within stage
#pragma unroll
      for (int mi = 0; mi < 4; ++mi) {
        const int r = wm * 64 + mi * 16 + (lane & 15);
        af[mi] = *(const s16x8*)(ldsA + r * 64 + (segk ^ (r & 7)) * 8);
      }
#pragma unroll
      for (int ni = 0; ni < 4; ++ni) {
        const int r = wn * 64 + ni * 16 + (lane & 15);
        bfr[ni] = *(const s16x8*)(ldsB + r * 64 + (segk ^ (r & 7)) * 8);
      }
#pragma unroll
      for (int mi = 0; mi < 4; ++mi)
#pragma unroll
        for (int ni = 0; ni < 4; ++ni)
          acc[mi][ni] = __builtin_amdgcn_mfma_f32_16x16x32_bf16(af[mi], bfr[ni], acc[mi][ni], 0, 0, 0);
    }
  }

  const int mode = *mmode;
  const int lanec = lane & 15, laneq = lane >> 4;
  const int wcol0 = col0 + wn * 64;  // wave spans exactly one 64-col group

  if (phase == 1) {
    // K section with fused kv_sum reduction
    const int n = (wcol0 - 1024) >> 6;   // head, uniform per wave
    const int b = row0 >> 13;            // batch (rows never cross b)
    float pc[4] = {0.f, 0.f, 0.f, 0.f};
#pragma unroll
    for (int mi = 0; mi < 4; ++mi) {
#pragma unroll
      for (int r = 0; r < 4; ++r) {
        const int row = row0 + wm * 64 + mi * 16 + laneq * 4 + r;
        const bool msk = get_mask(maskp, row, mode);
        if (!msk) {
          const float sv = sV[(size_t)row * NH + n];
#pragma unroll
          for (int ni = 0; ni < 4; ++ni) {
            const int col = wcol0 + ni * 16 + lanec;
            float v = acc[mi][ni][r] + bcat[col];
            float phi = v > 0.f ? v + 1.f : __expf(v);
            pc[ni] += phi * sv;
          }
        }
      }
    }
#pragma unroll
    for (int ni = 0; ni < 4; ++ni) {
      pc[ni] += __shfl_xor(pc[ni], 16);
      pc[ni] += __shfl_xor(pc[ni], 32);
    }
    if (laneq == 0) {
#pragma unroll
      for (int ni = 0; ni < 4; ++ni) {
        const int colk = wcol0 - 1024 + ni * 16 + lanec;  // 0..1023
        atomicAdd(&kv[b * DD + colk], pc[ni]);
      }
    }
  } else if (wcol0 < 2048) {
    // Q section -> phiQ
#pragma unroll
    for (int mi = 0; mi < 4; ++mi) {
#pragma unroll
      for (int r = 0; r < 4; ++r) {
        const int row = row0 + wm * 64 + mi * 16 + laneq * 4 + r;
#pragma unroll
        for (int ni = 0; ni < 4; ++ni) {
          const int col = wcol0 + ni * 16 + lanec;
          float v = acc[mi][ni][r] + bcat[col];
          float phi = v > 0.f ? v + 1.f : __expf(v);
          phiQ[(size_t)row * DD + col] = f2bf(phi);
        }
      }
    }
  } else {
    // WvS tile -> sV (only wn==0, ni==0, i.e. cols 2048..2063 are real)
    if (wn == 0) {
#pragma unroll
      for (int mi = 0; mi < 4; ++mi) {
#pragma unroll
        for (int r = 0; r < 4; ++r) {
          const int row = row0 + wm * 64 + mi * 16 + laneq * 4 + r;
          const bool msk = get_mask(maskp, row, mode);
          float v = acc[mi][0][r] + bcat[2048 + lanec];
          if (msk) v = 0.f;
          sV[(size_t)row * NH + lanec] = v;
        }
      }
    }
  }
}

// out[b,l,d] = phiQ[b,l,d] * kv_sum[b,d]
__global__ void finalize(const u16* __restrict__ phiQ, const float* __restrict__ kv_sum,
                         float* __restrict__ out) {
  const size_t i = (size_t)(blockIdx.x * 256 + threadIdx.x) * 4;
  const size_t b = i >> 23;  // / (8192*1024)
  const int d = (int)(i & 1023);
  u32 p0 = *(const u32*)(phiQ + i);
  u32 p1 = *(const u32*)(phiQ + i + 2);
  float4 kv = *(const float4*)(kv_sum + b * DD + d);
  float4 o;
  o.x = bf2f(p0 & 0xffffu) * kv.x;
  o.y = bf2f(p0 >> 16) * kv.y;
  o.z = bf2f(p1 & 0xffffu) * kv.z;
  o.w = bf2f(p1 >> 16) * kv.w;
  *(float4*)(out + i) = o;
}

extern "C" void kernel_launch(void* const* d_in, const int* in_sizes, int n_in,
                              void* d_out, int out_size, void* d_ws, size_t ws_size,
                              hipStream_t stream) {
  const float* query = (const float*)d_in[0];
  const void* maskp = d_in[1];
  const float* Wq = (const float*)d_in[2];
  const float* bq = (const float*)d_in[3];
  const float* Wk = (const float*)d_in[4];
  const float* bk = (const float*)d_in[5];
  const float* Wv = (const float*)d_in[6];
  const float* bv = (const float*)d_in[7];
  float* out = (float*)d_out;

  char* ws = (char*)d_ws;
  u16* qb = (u16*)ws;            ws += (size_t)MROWS * DD * 2;      // 64 MB
  u16* WbT = (u16*)ws;           ws += (size_t)NWBT * DD * 2;       // 4.25 MB
  u16* phiQ = (u16*)ws;          ws += (size_t)MROWS * DD * 2;      // 64 MB
  float* sV = (float*)ws;        ws += (size_t)MROWS * NH * 4;      // 2 MB
  float* bcat = (float*)ws;      ws += (size_t)NWBT * 4;
  float* kv = (float*)ws;        ws += (size_t)BB * DD * 4;         // 16 KB
  int* mflag = (int*)ws;         ws += 256;

  // zero kv_sum + mask-mode flag; zero the WbT pad rows (2064..2175)
  hipMemsetAsync(kv, 0, (size_t)BB * DD * 4 + 256, stream);
  hipMemsetAsync(WbT + (size_t)2064 * DD, 0, (size_t)112 * DD * 2, stream);

  detect_mask<<<32, 256, 0, stream>>>((const u32*)maskp, mflag);
  cvt_q<<<(MROWS * (DD / 4) + 255) / 256, 256, 0, stream>>>(query, qb, MROWS * (DD / 4));
  build_wbt<<<dim3(2048 / 32, DD / 32), dim3(32, 8), 0, stream>>>(Wq, Wk, WbT);
  build_wvs<<<64, 256, 0, stream>>>(Wv, WbT);
  build_bcat<<<(NWBT + 255) / 256, 256, 0, stream>>>(bq, bk, bv, bcat);
  // phase 0: Q tiles + WvS tile -> phiQ, sV
  gemm_qkv<<<dim3(MROWS / 128, 9), 256, 0, stream>>>(
      qb, WbT, bcat, maskp, mflag, phiQ, sV, kv, 0);
  // phase 1: K tiles -> kv_sum (fused reduction, no phiK materialization)
  gemm_qkv<<<dim3(MROWS / 128, 8), 256, 0, stream>>>(
      qb, WbT, bcat, maskp, mflag, phiQ, sV, kv, 1);
  finalize<<<(MROWS * DD / 4) / 256, 256, 0, stream>>>(phiQ, kv, out);
}